// Round 2
// baseline (291.507 us; speedup 1.0000x reference)
//
#include <hip/hip_runtime.h>

#define N_EMB 1024
#define D 64
#define NB 16
#define HW 4096            // 64*64
#define NTOK (NB * HW)     // 65536
#define KT 128             // codebook rows staged in LDS per tile

// ws: bn[1024] f32 at offset 0  (np-ordered ||e_k||^2)

// numpy pairwise sum, n=64 contiguous: 8 accumulators + fixed combine tree.
__device__ __forceinline__ float np_pairwise_sum64_sq(const float* v) {
    float s[8];
#pragma unroll
    for (int j = 0; j < 8; ++j) s[j] = __fmul_rn(v[j], v[j]);
#pragma unroll
    for (int i = 8; i < 64; i += 8) {
#pragma unroll
        for (int j = 0; j < 8; ++j)
            s[j] = __fadd_rn(s[j], __fmul_rn(v[i + j], v[i + j]));
    }
    return __fadd_rn(__fadd_rn(__fadd_rn(s[0], s[1]), __fadd_rn(s[2], s[3])),
                     __fadd_rn(__fadd_rn(s[4], s[5]), __fadd_rn(s[6], s[7])));
}

__global__ void k0_prep(const float* __restrict__ cb, float* __restrict__ bn) {
    int t = threadIdx.x;
    for (int k = t; k < N_EMB; k += 256) {
        float row[D];
        const float4* r4 = reinterpret_cast<const float4*>(cb + (size_t)k * D);
#pragma unroll
        for (int i = 0; i < 16; ++i) {
            float4 v = r4[i];
            row[4 * i + 0] = v.x; row[4 * i + 1] = v.y;
            row[4 * i + 2] = v.z; row[4 * i + 3] = v.w;
        }
        bn[k] = np_pairwise_sum64_sq(row);
    }
}

__global__ __launch_bounds__(256) void k1_argmin(
        const float* __restrict__ in, const float* __restrict__ cb,
        const float* __restrict__ bn_g, float* __restrict__ out) {
    __shared__ float se[KT][D];    // 32 KiB
    __shared__ float sbn[N_EMB];   // 4 KiB

    const int tid = threadIdx.x;
    const int tok = blockIdx.x * 256 + tid;
    const int b   = tok >> 12;
    const int hw  = tok & 4095;

    const float* in_tok = in + (size_t)b * (D * HW) + hw;
    float x[D];
#pragma unroll
    for (int d = 0; d < D; ++d) x[d] = in_tok[(size_t)d * HW];

    for (int k = tid; k < N_EMB; k += 256) sbn[k] = bn_g[k];

    // a = np.sum(x^2) with numpy's exact pairwise order
    const float a = np_pairwise_sum64_sq(x);

    float v1 = 3.402823466e+38f;   // FLT_MAX
    int   i1 = 0;

    for (int tile = 0; tile < N_EMB / KT; ++tile) {
        __syncthreads();
        const float4* src = reinterpret_cast<const float4*>(cb + (size_t)tile * KT * D);
        float4*       dst = reinterpret_cast<float4*>(&se[0][0]);
#pragma unroll
        for (int i = 0; i < 8; ++i) dst[tid + 256 * i] = src[tid + 256 * i];
        __syncthreads();

        for (int kk = 0; kk < KT; kk += 4) {
            const float4* e0 = reinterpret_cast<const float4*>(&se[kk + 0][0]);
            const float4* e1 = reinterpret_cast<const float4*>(&se[kk + 1][0]);
            const float4* e2 = reinterpret_cast<const float4*>(&se[kk + 2][0]);
            const float4* e3 = reinterpret_cast<const float4*>(&se[kk + 3][0]);
            float a0 = 0.f, a1 = 0.f, a2 = 0.f, a3 = 0.f;
            // BLAS sgemm microkernel order: sequential fma, k ascending,
            // one accumulator per output element.
#pragma unroll
            for (int i = 0; i < 16; ++i) {
                float4 u0 = e0[i], u1 = e1[i], u2 = e2[i], u3 = e3[i];
                float x0 = x[4 * i], x1 = x[4 * i + 1], x2 = x[4 * i + 2], x3 = x[4 * i + 3];
                a0 = __fmaf_rn(x0, u0.x, a0); a0 = __fmaf_rn(x1, u0.y, a0);
                a0 = __fmaf_rn(x2, u0.z, a0); a0 = __fmaf_rn(x3, u0.w, a0);
                a1 = __fmaf_rn(x0, u1.x, a1); a1 = __fmaf_rn(x1, u1.y, a1);
                a1 = __fmaf_rn(x2, u1.z, a1); a1 = __fmaf_rn(x3, u1.w, a1);
                a2 = __fmaf_rn(x0, u2.x, a2); a2 = __fmaf_rn(x1, u2.y, a2);
                a2 = __fmaf_rn(x2, u2.z, a2); a2 = __fmaf_rn(x3, u2.w, a2);
                a3 = __fmaf_rn(x0, u3.x, a3); a3 = __fmaf_rn(x1, u3.y, a3);
                a3 = __fmaf_rn(x2, u3.z, a3); a3 = __fmaf_rn(x3, u3.w, a3);
            }
            const int kb = tile * KT + kk;
            float acc[4] = {a0, a1, a2, a3};
#pragma unroll
            for (int u = 0; u < 4; ++u) {
                int   k = kb + u;
                // q = fl(fl(a + b_k) - fl(2*dot))  -- numpy's elementwise order
                float A = __fadd_rn(a, sbn[k]);
                float q = __fsub_rn(A, __fmul_rn(2.0f, acc[u]));
                if (q < v1) { v1 = q; i1 = k; }   // strict <, ascending k = first-min
            }
        }
    }

    float* out_tok = out + (size_t)b * (D * HW) + hw;
    const float4* erow = reinterpret_cast<const float4*>(cb + (size_t)i1 * D);
#pragma unroll
    for (int i = 0; i < 16; ++i) {
        float4 e = erow[i];
        out_tok[(size_t)(4 * i + 0) * HW] = e.x;
        out_tok[(size_t)(4 * i + 1) * HW] = e.y;
        out_tok[(size_t)(4 * i + 2) * HW] = e.z;
        out_tok[(size_t)(4 * i + 3) * HW] = e.w;
    }
}

extern "C" void kernel_launch(void* const* d_in, const int* in_sizes, int n_in,
                              void* d_out, int out_size, void* d_ws, size_t ws_size,
                              hipStream_t stream) {
    const float* in  = (const float*)d_in[0];
    const float* cb  = (const float*)d_in[1];
    float*       out = (float*)d_out;
    float*       bn  = (float*)d_ws;

    hipLaunchKernelGGL(k0_prep,   dim3(1),          dim3(256), 0, stream, cb, bn);
    hipLaunchKernelGGL(k1_argmin, dim3(NTOK / 256), dim3(256), 0, stream, in, cb, bn, out);
}

// Round 3
// 161.944 us; speedup vs baseline: 1.8000x; 1.8000x over previous
//
#include <hip/hip_runtime.h>

#define N_EMB 1024
#define D 64
#define HW 4096            // 64*64
#define NTOK 65536
#define KS 4               // codebook split factor (chunks)
#define CHUNK 256          // codes per chunk
#define KT 128             // codes staged per LDS tile

// ws layout: [0,4096) bn[1024] f32 ; [4096, 4096+NTOK*8) keys u64

// numpy pairwise sum of squares, n=64: 8 accumulators + fixed combine tree.
__device__ __forceinline__ float np_sum64_sq(const float* v) {
    float s[8];
#pragma unroll
    for (int j = 0; j < 8; ++j) s[j] = __fmul_rn(v[j], v[j]);
#pragma unroll
    for (int i = 8; i < 64; i += 8) {
#pragma unroll
        for (int j = 0; j < 8; ++j)
            s[j] = __fadd_rn(s[j], __fmul_rn(v[i + j], v[i + j]));
    }
    return __fadd_rn(__fadd_rn(__fadd_rn(s[0], s[1]), __fadd_rn(s[2], s[3])),
                     __fadd_rn(__fadd_rn(s[4], s[5]), __fadd_rn(s[6], s[7])));
}

__global__ void k0_prep(const float* __restrict__ cb, float* __restrict__ bn,
                        unsigned long long* __restrict__ keys) {
    int gid = blockIdx.x * 256 + threadIdx.x;
    keys[gid] = ~0ULL;
    if (blockIdx.x == 0) {
        for (int k = threadIdx.x; k < N_EMB; k += 256) {
            float row[D];
            const float4* r4 = reinterpret_cast<const float4*>(cb + (size_t)k * D);
#pragma unroll
            for (int i = 0; i < 16; ++i) {
                float4 v = r4[i];
                row[4 * i + 0] = v.x; row[4 * i + 1] = v.y;
                row[4 * i + 2] = v.z; row[4 * i + 3] = v.w;
            }
            bn[k] = np_sum64_sq(row);
        }
    }
}

__global__ __launch_bounds__(256, 4) void k1_argmin(
        const float* __restrict__ in, const float* __restrict__ cb,
        const float* __restrict__ bn_g, unsigned long long* __restrict__ keys) {
    __shared__ float se[KT][D];    // 32 KiB
    __shared__ float sbn[CHUNK];   // 1 KiB

    const int tid   = threadIdx.x;
    const int grp   = blockIdx.x >> 2;   // token group (consecutive blocks share x -> L2 hits)
    const int chunk = blockIdx.x & (KS - 1);
    const int tok   = grp * 256 + tid;
    const int b     = tok >> 12;
    const int hw    = tok & 4095;

    const float* in_tok = in + (size_t)b * (D * HW) + hw;
    float x[D];
#pragma unroll
    for (int d = 0; d < D; ++d) x[d] = in_tok[(size_t)d * HW];

    sbn[tid] = bn_g[chunk * CHUNK + tid];

    // a = np.sum(x^2, axis=1) in numpy's exact pairwise order
    const float a = np_sum64_sq(x);

    float v1 = 3.402823466e+38f;
    int   i1 = 0;

    const float* cb_chunk = cb + (size_t)chunk * CHUNK * D;

    for (int tile = 0; tile < CHUNK / KT; ++tile) {
        __syncthreads();
        const float4* src = reinterpret_cast<const float4*>(cb_chunk + (size_t)tile * KT * D);
        float4*       dst = reinterpret_cast<float4*>(&se[0][0]);
#pragma unroll
        for (int i = 0; i < 8; ++i) dst[tid + 256 * i] = src[tid + 256 * i];
        __syncthreads();

        for (int kk = 0; kk < KT; kk += 4) {
            const float4* e0 = reinterpret_cast<const float4*>(&se[kk + 0][0]);
            const float4* e1 = reinterpret_cast<const float4*>(&se[kk + 1][0]);
            const float4* e2 = reinterpret_cast<const float4*>(&se[kk + 2][0]);
            const float4* e3 = reinterpret_cast<const float4*>(&se[kk + 3][0]);
            float a0 = 0.f, a1 = 0.f, a2 = 0.f, a3 = 0.f;
            // frozen numerics: sequential fma, d ascending, one accumulator/code
#pragma unroll
            for (int i = 0; i < 16; ++i) {
                float4 u0 = e0[i], u1 = e1[i], u2 = e2[i], u3 = e3[i];
                float x0 = x[4 * i], x1 = x[4 * i + 1], x2 = x[4 * i + 2], x3 = x[4 * i + 3];
                a0 = __fmaf_rn(x0, u0.x, a0); a0 = __fmaf_rn(x1, u0.y, a0);
                a0 = __fmaf_rn(x2, u0.z, a0); a0 = __fmaf_rn(x3, u0.w, a0);
                a1 = __fmaf_rn(x0, u1.x, a1); a1 = __fmaf_rn(x1, u1.y, a1);
                a1 = __fmaf_rn(x2, u1.z, a1); a1 = __fmaf_rn(x3, u1.w, a1);
                a2 = __fmaf_rn(x0, u2.x, a2); a2 = __fmaf_rn(x1, u2.y, a2);
                a2 = __fmaf_rn(x2, u2.z, a2); a2 = __fmaf_rn(x3, u2.w, a2);
                a3 = __fmaf_rn(x0, u3.x, a3); a3 = __fmaf_rn(x1, u3.y, a3);
                a3 = __fmaf_rn(x2, u3.z, a3); a3 = __fmaf_rn(x3, u3.w, a3);
            }
            const int kl = tile * KT + kk;          // index within chunk
            float acc[4] = {a0, a1, a2, a3};
#pragma unroll
            for (int u = 0; u < 4; ++u) {
                // q = fl(fl(a + b_k) - fl(2*dot))  -- frozen
                float A = __fadd_rn(a, sbn[kl + u]);
                float q = __fsub_rn(A, __fmul_rn(2.0f, acc[u]));
                int   k = chunk * CHUNK + kl + u;
                if (q < v1) { v1 = q; i1 = k; }     // strict <, ascending k
            }
        }
    }

    // merge across chunks: positive fp32 bits are order-monotone as uint;
    // low word = index -> min key == (min q, then min k) == numpy argmin.
    unsigned long long key =
        ((unsigned long long)__float_as_uint(v1) << 32) | (unsigned int)i1;
    atomicMin(&keys[tok], key);
}

__global__ void k2_gather(const float* __restrict__ cb,
                          const unsigned long long* __restrict__ keys,
                          float* __restrict__ out) {
    int tok = blockIdx.x * 256 + threadIdx.x;
    int b = tok >> 12, hw = tok & 4095;
    unsigned int k = (unsigned int)(keys[tok] & 0xFFFFFFFFull);
    float* out_tok = out + (size_t)b * (D * HW) + hw;
    const float4* erow = reinterpret_cast<const float4*>(cb + (size_t)k * D);
#pragma unroll
    for (int i = 0; i < 16; ++i) {
        float4 e = erow[i];
        out_tok[(size_t)(4 * i + 0) * HW] = e.x;
        out_tok[(size_t)(4 * i + 1) * HW] = e.y;
        out_tok[(size_t)(4 * i + 2) * HW] = e.z;
        out_tok[(size_t)(4 * i + 3) * HW] = e.w;
    }
}

extern "C" void kernel_launch(void* const* d_in, const int* in_sizes, int n_in,
                              void* d_out, int out_size, void* d_ws, size_t ws_size,
                              hipStream_t stream) {
    const float* in  = (const float*)d_in[0];
    const float* cb  = (const float*)d_in[1];
    float*       out = (float*)d_out;
    char*        ws  = (char*)d_ws;
    float*               bn   = (float*)(ws);
    unsigned long long*  keys = (unsigned long long*)(ws + 4096);

    hipLaunchKernelGGL(k0_prep,   dim3(NTOK / 256),      dim3(256), 0, stream, cb, bn, keys);
    hipLaunchKernelGGL(k1_argmin, dim3(NTOK / 256 * KS), dim3(256), 0, stream, in, cb, bn, keys);
    hipLaunchKernelGGL(k2_gather, dim3(NTOK / 256),      dim3(256), 0, stream, cb, keys, out);
}